// Round 11
// baseline (222.181 us; speedup 1.0000x reference)
//
#include <hip/hip_runtime.h>
#include <hip/hip_bf16.h>

typedef _Float16 f16x8 __attribute__((ext_vector_type(8)));
typedef float f32x4 __attribute__((ext_vector_type(4)));

#define TAU_Q 132           // ceil(4e-3 * 32768): quantized margin threshold (proven at r7/r8)
#define MASK_Q 2098790u     // (64.05)*32768: best-below -> rescue (masked-proto / all-negative guard)

// ---------------- kernel 1: per-proto norm + split-fp16 pack ----------------
// q[m] = counts>0 ? 1/||p_m|| : 0. B-hat = P*q split into (hi, lo=residual) fp16, packed so
// MFMA B-fragment (p16=m>>4, kc) at lane L sits at byte (p16*8+kc)*1024 + L*16 (coalesced 1KB).
// Masked protos: qm=0 -> all-zero fragments -> dot contributes exactly 0.
__global__ __launch_bounds__(64) void prep_kernel(
    const float* __restrict__ P, const int* __restrict__ counts,
    float* __restrict__ q, int* __restrict__ wcount,
    f16x8* __restrict__ bhi, f16x8* __restrict__ blo) {
  const int m = blockIdx.x, lane = threadIdx.x;
  if (m == 0 && lane == 0) *wcount = 0;
  float4 v = *reinterpret_cast<const float4*>(P + (size_t)m * 256 + lane * 4);
  float s = v.x * v.x + v.y * v.y + v.z * v.z + v.w * v.w;
  for (int off = 32; off > 0; off >>= 1) s += __shfl_xor(s, off, 64);
  const float qm = (counts[m] > 0) ? (1.0f / sqrtf(s)) : 0.0f;
  if (lane == 0) q[m] = qm;
  if (lane < 32) {
    const int kg = lane;  // 8 k-elements per lane
    const float* src = P + (size_t)m * 256 + kg * 8;
    float4 v0 = *reinterpret_cast<const float4*>(src);
    float4 v1 = *reinterpret_cast<const float4*>(src + 4);
    float pe[8] = {v0.x, v0.y, v0.z, v0.w, v1.x, v1.y, v1.z, v1.w};
    f16x8 hi, lo;
#pragma unroll
    for (int t = 0; t < 8; ++t) {
      const float ph = pe[t] * qm;
      const _Float16 h = (_Float16)ph;
      hi[t] = h;
      lo[t] = (_Float16)(ph - (float)h);  // exact residual (Sterbenz), then rounded
    }
    const int dst = ((m >> 4) * 8 + (kg >> 2)) * 64 + (kg & 3) * 16 + (m & 15);
    bhi[dst] = hi;
    blo[dst] = lo;
  }
}

// ---------------- kernel 2: 2-term split-fp16 MFMA screen ----------------
// 256 threads = 4 waves (2 rg x 2 cg). BM=128 rows; wave = 64 rows x 64 protos per pt-iter.
// rg-waves own disjoint rows -> barrier-free main loop; cg pair merged at the end via LDS.
// A: E hi fp16, K=256, 64KB LDS (-> 2 blocks/CU = 2 waves/SIMD), XOR-swizzled.
// B: pre-packed (hi,lo) fragments, global->VGPR, manual 2-step ping-pong with NAMED sets.
// REGISTER POLICY (hard-won): plain __launch_bounds__(256) is the ONLY config observed to
// grant >128 arch-VGPRs (r8: 184, zero spill). 512-thread kernels and ANY second
// launch-bounds arg clamp to 128 and spill ~85MB/dispatch (r5/r6/r7/r9/r10).
__global__ __launch_bounds__(256) void screen_kernel(
    const float* __restrict__ E, const f16x8* __restrict__ bhi,
    const f16x8* __restrict__ blo, int* __restrict__ out,
    int* __restrict__ wcount, int* __restrict__ wl, int wlcap) {
  __shared__ __align__(16) unsigned char ldsA[65536];  // 128 rows x 512B (hi fp16, K=256)

  const int tid = threadIdx.x;
  const int wave = tid >> 6, lane = tid & 63;
  const int rg = wave >> 1, cg = wave & 1;
  const int g = lane >> 4, c = lane & 15;
  const int blockRow = blockIdx.x * 128;

  // ---- stage A once: E[blockRow..+128][0..256) f32 -> hi fp16, swizzled ----
  {
    const int row = tid >> 1, half = tid & 1;  // 2 threads/row, 128 k each
    const float* src = E + (size_t)(blockRow + row) * 256 + half * 128;
    const int rswz = (row & 7) << 4;
#pragma unroll
    for (int o = 0; o < 16; ++o) {
      float4 v0 = *reinterpret_cast<const float4*>(src + o * 8);
      float4 v1 = *reinterpret_cast<const float4*>(src + o * 8 + 4);
      float e[8] = {v0.x, v0.y, v0.z, v0.w, v1.x, v1.y, v1.z, v1.w};
      f16x8 hi;
#pragma unroll
      for (int t = 0; t < 8; ++t) hi[t] = (_Float16)e[t];
      const int byte = (row * 512 + (half * 128 + o * 8) * 2) ^ rswz;
      *reinterpret_cast<f16x8*>(ldsA + byte) = hi;
    }
  }
  __syncthreads();

  // packed top-2 per lane: 16 row-slots (row = rg*64 + (s>>2)*16 + g*4 + (s&3))
  unsigned t1[16], t2[16];
#pragma unroll
  for (int s = 0; s < 16; ++s) { t1[s] = 0u; t2[s] = 0u; }

  const char* bhiB = (const char*)bhi + (size_t)lane * 16;
  const char* bloB = (const char*)blo + (size_t)lane * 16;

#define LOAD_A(dst, kcv)                                                     \
  {                                                                          \
    _Pragma("unroll") for (int fr = 0; fr < 4; ++fr) {                       \
      const int rowA = rg * 64 + fr * 16 + c;                                \
      const int ab = (rowA * 512 + (kcv)*64 + g * 16) ^ ((rowA & 7) << 4);   \
      dst[fr] = *reinterpret_cast<const f16x8*>(ldsA + ab);                  \
    }                                                                        \
  }
#define LOAD_B(dh, dl, ptv, kcv)                                             \
  {                                                                          \
    _Pragma("unroll") for (int fc = 0; fc < 4; ++fc) {                       \
      const size_t ch =                                                      \
          (size_t)((((ptv)*8 + cg * 4 + fc) * 8 + (kcv)) << 10);             \
      dh[fc] = *reinterpret_cast<const f16x8*>(bhiB + ch);                   \
      dl[fc] = *reinterpret_cast<const f16x8*>(bloB + ch);                   \
    }                                                                        \
  }
#define MFMA32(av, bhv, blv)                                                 \
  {                                                                          \
    _Pragma("unroll") for (int fr = 0; fr < 4; ++fr)                         \
        _Pragma("unroll") for (int fc = 0; fc < 4; ++fc)                     \
        acc[fr][fc] = __builtin_amdgcn_mfma_f32_16x16x32_f16(                \
            av[fr], bhv[fc], acc[fr][fc], 0, 0, 0);                          \
    _Pragma("unroll") for (int fr = 0; fr < 4; ++fr)                         \
        _Pragma("unroll") for (int fc = 0; fc < 4; ++fc)                     \
        acc[fr][fc] = __builtin_amdgcn_mfma_f32_16x16x32_f16(                \
            av[fr], blv[fc], acc[fr][fc], 0, 0, 0);                          \
  }

  f16x8 a0[4], a1[4], bh0[4], bl0[4], bh1[4], bl1[4];
  LOAD_A(a0, 0);
  LOAD_B(bh0, bl0, 0, 0);

#pragma unroll 1
  for (int pt = 0; pt < 8; ++pt) {
    f32x4 acc[4][4];
#pragma unroll
    for (int fr = 0; fr < 4; ++fr)
#pragma unroll
      for (int fc = 0; fc < 4; ++fc) acc[fr][fc] = (f32x4){0.f, 0.f, 0.f, 0.f};

#pragma unroll
    for (int pair = 0; pair < 4; ++pair) {
      // body even: t = pt*8 + pair*2, uses set0; prefetch set1 <- t+1
      {
        const int tn = pt * 8 + pair * 2 + 1;  // <= 63 always
        const int ptn = tn >> 3, kcn = tn & 7;
        LOAD_B(bh1, bl1, ptn, kcn);
        LOAD_A(a1, kcn);
        MFMA32(a0, bh0, bl0);
      }
      // body odd: t+1, uses set1; prefetch set0 <- t+2 (wraps harmlessly at end)
      {
        const int tn = (pt * 8 + pair * 2 + 2) & 63;
        const int ptn = tn >> 3, kcn = tn & 7;
        LOAD_B(bh0, bl0, ptn, kcn);
        LOAD_A(a0, kcn);
        MFMA32(a1, bh1, bl1);
      }
    }

    // ---- fold this pt's 64 proto-columns (per cg) into packed top-2 ----
#pragma unroll
    for (int fc = 0; fc < 4; ++fc) {
      const unsigned mp = (unsigned)(1023 - (pt * 128 + cg * 64 + fc * 16 + c));
#pragma unroll
      for (int fr = 0; fr < 4; ++fr)
#pragma unroll
        for (int reg = 0; reg < 4; ++reg) {
          const int s = fr * 4 + reg;
          const float v = acc[fr][fc][reg];
          const unsigned k = ((unsigned)fmaf(v, 32768.0f, 2097152.0f) << 10) | mp;
          const unsigned lo = (k < t1[s]) ? k : t1[s];
          t1[s] = (k > t1[s]) ? k : t1[s];
          t2[s] = (lo > t2[s]) ? lo : t2[s];
        }
    }
  }

  // ---- cross-lane top-2 merge over the 16 c-lanes sharing each row ----
#pragma unroll
  for (int s = 0; s < 16; ++s) {
#pragma unroll
    for (int off = 1; off <= 8; off <<= 1) {
      const unsigned o1 = (unsigned)__shfl_xor((int)t1[s], off);
      const unsigned o2 = (unsigned)__shfl_xor((int)t2[s], off);
      const unsigned lo = (o1 < t1[s]) ? o1 : t1[s];
      t1[s] = (o1 > t1[s]) ? o1 : t1[s];
      const unsigned hi2 = (o2 > t2[s]) ? o2 : t2[s];
      t2[s] = (lo > hi2) ? lo : hi2;
    }
  }

  __syncthreads();  // all waves done with ldsA -> reuse for cross-cg merge
  unsigned* mg = reinterpret_cast<unsigned*>(ldsA);  // [128 rows][2 cg][2]
  if (c == 0) {
#pragma unroll
    for (int s = 0; s < 16; ++s) {
      const int row = rg * 64 + (s >> 2) * 16 + g * 4 + (s & 3);
      mg[(row * 2 + cg) * 2 + 0] = t1[s];
      mg[(row * 2 + cg) * 2 + 1] = t2[s];
    }
  }
  __syncthreads();
  if (tid < 128) {
    const unsigned a1v = mg[(tid * 2 + 0) * 2 + 0], a2v = mg[(tid * 2 + 0) * 2 + 1];
    const unsigned b1v = mg[(tid * 2 + 1) * 2 + 0], b2v = mg[(tid * 2 + 1) * 2 + 1];
    const unsigned lo = (a1v < b1v) ? a1v : b1v;
    const unsigned T1 = (a1v > b1v) ? a1v : b1v;
    unsigned T2 = (a2v > b2v) ? a2v : b2v;
    T2 = (lo > T2) ? lo : T2;
    const int grow = blockRow + tid;
    out[grow] = 1023 - (int)(T1 & 1023u);
    const unsigned iq1 = T1 >> 10, iq2 = T2 >> 10;
    if ((int)(iq1 - iq2) < TAU_Q || iq1 < MASK_Q) {
      const int p = atomicAdd(wcount, 1);
      if (p < wlcap) wl[p] = grow;
    }
  }
#undef LOAD_A
#undef LOAD_B
#undef MFMA32
}

// ---------------- kernel 3: exact f32 rescue over the worklist ----------------
// Round-1-identical accumulation per (row, proto): single ascending-k fmaf chain
// (x,y,z,w within each float4), then v = acc*q, ties to the smaller proto index.
__global__ __launch_bounds__(256) void rescue_kernel(
    const float* __restrict__ E, const float* __restrict__ P,
    const float* __restrict__ q, int* __restrict__ out,
    const int* __restrict__ wcount, const int* __restrict__ wl, int wlcap) {
  __shared__ float Elds[8][260];
  __shared__ int rowsS[8];
  __shared__ float wv[8][4];
  __shared__ int wm[8][4];

  const int tid = threadIdx.x;
  const int wave = tid >> 6, lane = tid & 63;
  int total = *wcount;
  if (total > wlcap) total = wlcap;

  for (int b0 = blockIdx.x * 8; b0 < total; b0 += gridDim.x * 8) {
    const int nb = min(8, total - b0);
    __syncthreads();
    if (tid < 8) rowsS[tid] = wl[b0 + (tid < nb ? tid : 0)];
    __syncthreads();
#pragma unroll
    for (int u = 0; u < 2; ++u) {
      const int unit = u * 256 + tid, r = unit >> 6, k4 = unit & 63;
      *reinterpret_cast<float4*>(&Elds[r][k4 * 4]) =
          *reinterpret_cast<const float4*>(E + (size_t)rowsS[r] * 256 + k4 * 4);
    }
    __syncthreads();

    float acc[8][4];  // 8 rows x 4 protos (m = tid + 256*j)
#pragma unroll
    for (int r = 0; r < 8; ++r)
#pragma unroll
      for (int j = 0; j < 4; ++j) acc[r][j] = 0.f;

#pragma unroll 2
    for (int k4 = 0; k4 < 64; ++k4) {
      float4 pv[4];
#pragma unroll
      for (int j = 0; j < 4; ++j)
        pv[j] = *reinterpret_cast<const float4*>(P + (size_t)(tid + 256 * j) * 256 + k4 * 4);
      float4 ev[8];
#pragma unroll
      for (int r = 0; r < 8; ++r) ev[r] = *reinterpret_cast<const float4*>(&Elds[r][k4 * 4]);
#pragma unroll
      for (int r = 0; r < 8; ++r)
#pragma unroll
        for (int j = 0; j < 4; ++j) {
          float a = acc[r][j];
          a = fmaf(pv[j].x, ev[r].x, a);
          a = fmaf(pv[j].y, ev[r].y, a);
          a = fmaf(pv[j].z, ev[r].z, a);
          a = fmaf(pv[j].w, ev[r].w, a);
          acc[r][j] = a;
        }
    }

    float qv[4];
#pragma unroll
    for (int j = 0; j < 4; ++j) qv[j] = q[tid + 256 * j];

#pragma unroll
    for (int r = 0; r < 8; ++r) {
      float bv = -3.0e38f;
      int bm = 0;
#pragma unroll
      for (int j = 0; j < 4; ++j) {  // m ascending -> strict > keeps lowest m
        const float v = (qv[j] > 0.f) ? acc[r][j] * qv[j] : -1.0e30f;
        if (v > bv) { bv = v; bm = tid + 256 * j; }
      }
#pragma unroll
      for (int off = 1; off <= 32; off <<= 1) {
        const float ov = __shfl_xor(bv, off);
        const int om = __shfl_xor(bm, off);
        if (ov > bv || (ov == bv && om < bm)) { bv = ov; bm = om; }
      }
      if (lane == 0) { wv[r][wave] = bv; wm[r][wave] = bm; }
    }
    __syncthreads();
    if (tid < 8) {
      float bv = wv[tid][0];
      int bm = wm[tid][0];
#pragma unroll
      for (int w = 1; w < 4; ++w) {
        const float ov = wv[tid][w];
        const int om = wm[tid][w];
        if (ov > bv || (ov == bv && om < bm)) { bv = ov; bm = om; }
      }
      if (tid < nb) out[rowsS[tid]] = bm;
    }
    __syncthreads();
  }
}

extern "C" void kernel_launch(void* const* d_in, const int* in_sizes, int n_in,
                              void* d_out, int out_size, void* d_ws, size_t ws_size,
                              hipStream_t stream) {
  const float* E = (const float*)d_in[0];
  const float* P = (const float*)d_in[1];
  const int* counts = (const int*)d_in[2];
  const int M = in_sizes[2];            // 1024
  const int Dd = in_sizes[1] / M;       // 256
  const int N = in_sizes[0] / Dd;       // 65536
  int* out = (int*)d_out;

  // workspace: q (4KB) | wcount @4096 | bhi @8192 (512KB) | blo @532480 (512KB) | worklist @1056768
  float* qv = (float*)d_ws;
  int* wcount = (int*)((char*)d_ws + 4096);
  f16x8* bhi = (f16x8*)((char*)d_ws + 8192);
  f16x8* blo = (f16x8*)((char*)d_ws + 8192 + 524288);
  int* wl = (int*)((char*)d_ws + 8192 + 1048576);
  long long cap = ((long long)ws_size - (8192 + 1048576)) / 4;
  if (cap < 0) cap = 0;
  if (cap > N) cap = N;
  int wlcap = (int)cap;

  prep_kernel<<<M, 64, 0, stream>>>(P, counts, qv, wcount, bhi, blo);
  screen_kernel<<<N / 128, 256, 0, stream>>>(E, bhi, blo, out, wcount, wl, wlcap);
  rescue_kernel<<<256, 256, 0, stream>>>(E, P, qv, out, wcount, wl, wlcap);
}

// Round 12
// 135.842 us; speedup vs baseline: 1.6356x; 1.6356x over previous
//
#include <hip/hip_runtime.h>
#include <hip/hip_bf16.h>

typedef _Float16 f16x8 __attribute__((ext_vector_type(8)));
typedef float f32x4 __attribute__((ext_vector_type(4)));

#define TAU_Q 164           // ceil(5e-3 * 32768) = 10 sigma of 1-term fp16 dot noise (sigma~5e-4)
#define MASK_Q 2098790u     // (64.05)*32768: best-below -> rescue (masked-proto / all-negative guard)

typedef const __attribute__((address_space(1))) void gas_void;
typedef __attribute__((address_space(3))) void las_void;

__device__ __forceinline__ void gload_lds16(const void* g, void* l) {
  // async global->LDS DMA, 16B/lane; LDS dest = wave-uniform base + lane*16
  __builtin_amdgcn_global_load_lds((gas_void*)g, (las_void*)l, 16, 0, 0);
}

// ---------------- kernel 1: per-proto norm + fp16-hi pack ----------------
// q[m] = counts>0 ? 1/||p_m|| : 0. B-hat = fp16(P*q), packed so MFMA B-fragment
// (p16=m>>4, kc) at lane L sits at byte (p16*8+kc)*1024 + L*16 (coalesced 1KB chunks).
// Masked protos: qm=0 -> all-zero fragments -> dot contributes exactly 0 (caught by MASK_Q).
__global__ __launch_bounds__(64) void prep_kernel(
    const float* __restrict__ P, const int* __restrict__ counts,
    float* __restrict__ q, int* __restrict__ wcount, f16x8* __restrict__ bhi) {
  const int m = blockIdx.x, lane = threadIdx.x;
  if (m == 0 && lane == 0) *wcount = 0;
  float4 v = *reinterpret_cast<const float4*>(P + (size_t)m * 256 + lane * 4);
  float s = v.x * v.x + v.y * v.y + v.z * v.z + v.w * v.w;
  for (int off = 32; off > 0; off >>= 1) s += __shfl_xor(s, off, 64);
  const float qm = (counts[m] > 0) ? (1.0f / sqrtf(s)) : 0.0f;
  if (lane == 0) q[m] = qm;
  if (lane < 32) {
    const int kg = lane;  // 8 k-elements per lane
    const float* src = P + (size_t)m * 256 + kg * 8;
    float4 v0 = *reinterpret_cast<const float4*>(src);
    float4 v1 = *reinterpret_cast<const float4*>(src + 4);
    float pe[8] = {v0.x, v0.y, v0.z, v0.w, v1.x, v1.y, v1.z, v1.w};
    f16x8 hi;
#pragma unroll
    for (int t = 0; t < 8; ++t) hi[t] = (_Float16)(pe[t] * qm);
    const int dst = ((m >> 4) * 8 + (kg >> 2)) * 64 + (kg & 3) * 16 + (m & 15);
    bhi[dst] = hi;
  }
}

// ---------------- kernel 2: 1-term fp16 MFMA screen (r7 structure, hi-only B) ----------------
// 512 threads = 8 waves (2 rg x 4 cg). BM=128 rows; wave tile 64 rows x 64 protos per step.
// A: E hi fp16, K=256, 64KB LDS, XOR-swizzled (one stage barrier).
// B: hi-only packed fragments DMA'd per (pt,kc) step into 2x16KB LDS double buffer via
// global_load_lds (issued BEFORE the MFMA cluster; barrier at step end drains it).
// B traffic halves vs r7 (the measured wall was B bandwidth ~4 TB/s effective: 512->256MB).
// Top-2 kept quantized-packed: ((v+64)*2^15)<<10 | (1023-m) (quantum 3e-5, tie->lowest m).
__global__ __launch_bounds__(512) void screen_kernel(
    const float* __restrict__ E, const f16x8* __restrict__ bhi,
    int* __restrict__ out, int* __restrict__ wcount,
    int* __restrict__ wl, int wlcap) {
  __shared__ __align__(16) unsigned char ldsA[65536];  // 128 rows x 512B (hi fp16, K=256)
  __shared__ __align__(16) unsigned char ldsB[32768];  // 2 bufs x 16KB (16 chunks of 1KB)

  const int tid = threadIdx.x;
  const int wave = tid >> 6, lane = tid & 63;
  const int rg = wave >> 2, cg = wave & 3;
  const int g = lane >> 4, c = lane & 15;
  const int blockRow = blockIdx.x * 128;
  const char* bhiB = (const char*)bhi;

  // ---- stage A once: E[blockRow..+128][0..256) f32 -> hi fp16, swizzled ----
  {
    const int row = tid >> 2, qq = tid & 3;  // 4 threads/row, 64 k each
    const float* src = E + (size_t)(blockRow + row) * 256 + qq * 64;
    const int rswz = (row & 7) << 4;
#pragma unroll
    for (int o = 0; o < 8; ++o) {
      float4 v0 = *reinterpret_cast<const float4*>(src + o * 8);
      float4 v1 = *reinterpret_cast<const float4*>(src + o * 8 + 4);
      float e[8] = {v0.x, v0.y, v0.z, v0.w, v1.x, v1.y, v1.z, v1.w};
      f16x8 hi;
#pragma unroll
      for (int t = 0; t < 8; ++t) hi[t] = (_Float16)e[t];
      const int byte = (row * 512 + (qq * 64 + o * 8) * 2) ^ rswz;
      *reinterpret_cast<f16x8*>(ldsA + byte) = hi;
    }
  }

  // ---- B stage: DMA step t=(pt,kc) into buffer b (each wave: 2 hi chunks) ----
  const int chunk = wave * 2;
  auto stageB = [&](int b, int t) {
    const int ptn = t >> 3, kcn = t & 7;
    const size_t src = (size_t)(((ptn * 16 + chunk) * 8 + kcn) * 1024) + (size_t)lane * 16;
    char* dstb = (char*)ldsB + b * 16384 + chunk * 1024;
    gload_lds16(bhiB + src, dstb);
    gload_lds16(bhiB + src + 8192, dstb + 1024);  // chunk+1: src stride 8KB
  };

  stageB(0, 0);
  __syncthreads();  // A staged + first B landed

  // quantized top-2 per lane: 16 row-slots (row = rg*64 + (s>>2)*16 + g*4 + (s&3))
  unsigned t1[16], t2[16];
#pragma unroll
  for (int s = 0; s < 16; ++s) { t1[s] = 0u; t2[s] = 0u; }

  int buf = 0;
  for (int pt = 0; pt < 4; ++pt) {
    f32x4 acc[4][4];
#pragma unroll
    for (int fr = 0; fr < 4; ++fr)
#pragma unroll
      for (int fc = 0; fc < 4; ++fc) acc[fr][fc] = (f32x4){0.f, 0.f, 0.f, 0.f};

    for (int kc = 0; kc < 8; ++kc) {
      const int t = pt * 8 + kc;
      if (t < 31) stageB(buf ^ 1, t + 1);  // DMA next step; hides under MFMA below

      // ---- A fragments (hi) from LDS ----
      f16x8 ah[4];
#pragma unroll
      for (int fr = 0; fr < 4; ++fr) {
        const int rowA = rg * 64 + fr * 16 + c;
        const int ab = (rowA * 512 + kc * 64 + g * 16) ^ ((rowA & 7) << 4);
        ah[fr] = *reinterpret_cast<const f16x8*>(ldsA + ab);
      }
      // ---- B fragments (hi) from LDS, then 16 MFMA ----
      const char* bbase = (const char*)ldsB + buf * 16384 + (cg * 4) * 1024 + (size_t)lane * 16;
      f16x8 bf[4];
#pragma unroll
      for (int fc = 0; fc < 4; ++fc) bf[fc] = *reinterpret_cast<const f16x8*>(bbase + fc * 1024);
#pragma unroll
      for (int fr = 0; fr < 4; ++fr)
#pragma unroll
        for (int fc = 0; fc < 4; ++fc)
          acc[fr][fc] = __builtin_amdgcn_mfma_f32_16x16x32_f16(ah[fr], bf[fc], acc[fr][fc], 0, 0, 0);

      __syncthreads();  // drains the DMA (vmcnt) + all waves done reading buf
      buf ^= 1;
    }

    // ---- fold this pt's 64 proto-columns (per cg) into quantized top-2 ----
#pragma unroll
    for (int fc = 0; fc < 4; ++fc) {
      const unsigned mp = (unsigned)(1023 - (pt * 256 + cg * 64 + fc * 16 + c));
#pragma unroll
      for (int fr = 0; fr < 4; ++fr)
#pragma unroll
        for (int reg = 0; reg < 4; ++reg) {
          const int s = fr * 4 + reg;
          const float v = acc[fr][fc][reg];
          const unsigned k = ((unsigned)fmaf(v, 32768.0f, 2097152.0f) << 10) | mp;
          const unsigned lo = (k < t1[s]) ? k : t1[s];
          t1[s] = (k > t1[s]) ? k : t1[s];
          t2[s] = (lo > t2[s]) ? lo : t2[s];
        }
    }
  }

  // ---- cross-lane top-2 merge over the 16 c-lanes sharing each row ----
#pragma unroll
  for (int s = 0; s < 16; ++s) {
#pragma unroll
    for (int off = 1; off <= 8; off <<= 1) {
      const unsigned o1 = (unsigned)__shfl_xor((int)t1[s], off);
      const unsigned o2 = (unsigned)__shfl_xor((int)t2[s], off);
      const unsigned lo = (o1 < t1[s]) ? o1 : t1[s];
      t1[s] = (o1 > t1[s]) ? o1 : t1[s];
      const unsigned hi2 = (o2 > t2[s]) ? o2 : t2[s];
      t2[s] = (lo > hi2) ? lo : hi2;
    }
  }

  __syncthreads();  // all LDS use done -> reuse ldsA for cross-cg merge
  unsigned* mg = reinterpret_cast<unsigned*>(ldsA);  // [128 rows][4 cg][2]
  if (c == 0) {
#pragma unroll
    for (int s = 0; s < 16; ++s) {
      const int row = rg * 64 + (s >> 2) * 16 + g * 4 + (s & 3);
      mg[(row * 4 + cg) * 2 + 0] = t1[s];
      mg[(row * 4 + cg) * 2 + 1] = t2[s];
    }
  }
  __syncthreads();
  if (tid < 128) {
    unsigned T1 = mg[(tid * 4 + 0) * 2 + 0], T2 = mg[(tid * 4 + 0) * 2 + 1];
#pragma unroll
    for (int w = 1; w < 4; ++w) {
      const unsigned o1 = mg[(tid * 4 + w) * 2 + 0], o2 = mg[(tid * 4 + w) * 2 + 1];
      const unsigned lo = (o1 < T1) ? o1 : T1;
      T1 = (o1 > T1) ? o1 : T1;
      const unsigned hi2 = (o2 > T2) ? o2 : T2;
      T2 = (lo > hi2) ? lo : hi2;
    }
    const int grow = blockRow + tid;
    out[grow] = 1023 - (int)(T1 & 1023u);
    const unsigned iq1 = T1 >> 10, iq2 = T2 >> 10;
    if ((int)(iq1 - iq2) < TAU_Q || iq1 < MASK_Q) {
      const int p = atomicAdd(wcount, 1);
      if (p < wlcap) wl[p] = grow;
    }
  }
}

// ---------------- kernel 3: exact f32 rescue over the worklist (16 rows/batch) ----------------
// Round-1-identical accumulation per (row, proto): ONE ascending-k fmaf chain over k=0..255
// (x,y,z,w within each float4), then v = acc*q, ties to the smaller proto index.
// E rows staged in LDS (broadcast reads); P read 64B-consecutive per thread per k16-step.
__global__ __launch_bounds__(256) void rescue_kernel(
    const float* __restrict__ E, const float* __restrict__ P,
    const float* __restrict__ q, int* __restrict__ out,
    const int* __restrict__ wcount, const int* __restrict__ wl, int wlcap) {
  __shared__ float Elds[16][260];
  __shared__ int rowsS[16];
  __shared__ float wv[16][4];
  __shared__ int wm[16][4];

  const int tid = threadIdx.x;
  const int wave = tid >> 6, lane = tid & 63;
  int total = *wcount;
  if (total > wlcap) total = wlcap;

  for (int b0 = blockIdx.x * 16; b0 < total; b0 += gridDim.x * 16) {
    const int nb = min(16, total - b0);
    __syncthreads();
    if (tid < 16) rowsS[tid] = wl[b0 + (tid < nb ? tid : 0)];
    __syncthreads();
#pragma unroll
    for (int u = 0; u < 4; ++u) {
      const int unit = u * 256 + tid, r = unit >> 6, k4 = unit & 63;
      *reinterpret_cast<float4*>(&Elds[r][k4 * 4]) =
          *reinterpret_cast<const float4*>(E + (size_t)rowsS[r] * 256 + k4 * 4);
    }
    __syncthreads();

    float acc[16][4];  // 16 rows x 4 protos (m = tid + 256*j)
#pragma unroll
    for (int r = 0; r < 16; ++r)
#pragma unroll
      for (int j = 0; j < 4; ++j) acc[r][j] = 0.f;

    for (int k16 = 0; k16 < 16; ++k16) {  // 16 consecutive k per step
#pragma unroll
      for (int jp = 0; jp < 2; ++jp) {    // protos in pairs (register budget)
        float4 pv[2][4];
#pragma unroll
        for (int jj = 0; jj < 2; ++jj) {
          const float* ps = P + (size_t)(tid + 256 * (jp * 2 + jj)) * 256 + k16 * 16;
#pragma unroll
          for (int u = 0; u < 4; ++u)
            pv[jj][u] = *reinterpret_cast<const float4*>(ps + u * 4);
        }
#pragma unroll
        for (int r = 0; r < 16; ++r) {
#pragma unroll
          for (int jj = 0; jj < 2; ++jj) {
            const int j = jp * 2 + jj;
            float a = acc[r][j];
#pragma unroll
            for (int u = 0; u < 4; ++u) {
              const float4 ev = *reinterpret_cast<const float4*>(&Elds[r][k16 * 16 + u * 4]);
              a = fmaf(pv[jj][u].x, ev.x, a);
              a = fmaf(pv[jj][u].y, ev.y, a);
              a = fmaf(pv[jj][u].z, ev.z, a);
              a = fmaf(pv[jj][u].w, ev.w, a);
            }
            acc[r][j] = a;
          }
        }
      }
    }

    float qv[4];
#pragma unroll
    for (int j = 0; j < 4; ++j) qv[j] = q[tid + 256 * j];

#pragma unroll
    for (int r = 0; r < 16; ++r) {
      float bv = -3.0e38f;
      int bm = 0;
#pragma unroll
      for (int j = 0; j < 4; ++j) {  // m ascending -> strict > keeps lowest m
        const float v = (qv[j] > 0.f) ? acc[r][j] * qv[j] : -1.0e30f;
        if (v > bv) { bv = v; bm = tid + 256 * j; }
      }
#pragma unroll
      for (int off = 1; off <= 32; off <<= 1) {
        const float ov = __shfl_xor(bv, off);
        const int om = __shfl_xor(bm, off);
        if (ov > bv || (ov == bv && om < bm)) { bv = ov; bm = om; }
      }
      if (lane == 0) { wv[r][wave] = bv; wm[r][wave] = bm; }
    }
    __syncthreads();
    if (tid < 16) {
      float bv = wv[tid][0];
      int bm = wm[tid][0];
#pragma unroll
      for (int w = 1; w < 4; ++w) {
        const float ov = wv[tid][w];
        const int om = wm[tid][w];
        if (ov > bv || (ov == bv && om < bm)) { bv = ov; bm = om; }
      }
      if (tid < nb) out[rowsS[tid]] = bm;
    }
    __syncthreads();
  }
}

extern "C" void kernel_launch(void* const* d_in, const int* in_sizes, int n_in,
                              void* d_out, int out_size, void* d_ws, size_t ws_size,
                              hipStream_t stream) {
  const float* E = (const float*)d_in[0];
  const float* P = (const float*)d_in[1];
  const int* counts = (const int*)d_in[2];
  const int M = in_sizes[2];            // 1024
  const int Dd = in_sizes[1] / M;       // 256
  const int N = in_sizes[0] / Dd;       // 65536
  int* out = (int*)d_out;

  // workspace: q (4KB) | wcount @4096 | bhi @8192 (512KB) | worklist @532480
  float* qv = (float*)d_ws;
  int* wcount = (int*)((char*)d_ws + 4096);
  f16x8* bhi = (f16x8*)((char*)d_ws + 8192);
  int* wl = (int*)((char*)d_ws + 8192 + 524288);
  long long cap = ((long long)ws_size - (8192 + 524288)) / 4;
  if (cap < 0) cap = 0;
  if (cap > N) cap = N;
  int wlcap = (int)cap;

  prep_kernel<<<M, 64, 0, stream>>>(P, counts, qv, wcount, bhi);
  screen_kernel<<<N / 128, 512, 0, stream>>>(E, bhi, out, wcount, wl, wlcap);
  rescue_kernel<<<256, 256, 0, stream>>>(E, P, qv, out, wcount, wl, wlcap);
}

// Round 14
// 121.586 us; speedup vs baseline: 1.8274x; 1.1173x over previous
//
#include <hip/hip_runtime.h>
#include <hip/hip_bf16.h>

typedef _Float16 f16x8 __attribute__((ext_vector_type(8)));
typedef float f32x4 __attribute__((ext_vector_type(4)));

#define TAU_Q 164           // ceil(5e-3 * 32768) = 10 sigma of 1-term fp16 dot noise (sigma~5e-4)
#define MASK_Q 2098790u     // (64.05)*32768: best-below -> rescue (masked-proto / all-negative guard)

typedef const __attribute__((address_space(1))) void gas_void;
typedef __attribute__((address_space(3))) void las_void;

__device__ __forceinline__ void gload_lds16(const void* g, void* l) {
  // async global->LDS DMA, 16B/lane; LDS dest = wave-uniform base + lane*16
  __builtin_amdgcn_global_load_lds((gas_void*)g, (las_void*)l, 16, 0, 0);
}

// ---------------- kernel 1: per-proto norm + fp16-hi pack ----------------
// q[m] = counts>0 ? 1/||p_m|| : 0. B-hat = fp16(P*q), packed so MFMA B-fragment
// (p16=m>>4, kc) at lane L sits at byte (p16*8+kc)*1024 + L*16 (coalesced 1KB chunks).
// Masked protos: qm=0 -> all-zero fragments -> dot contributes exactly 0 (caught by MASK_Q).
__global__ __launch_bounds__(64) void prep_kernel(
    const float* __restrict__ P, const int* __restrict__ counts,
    float* __restrict__ q, int* __restrict__ wcount, f16x8* __restrict__ bhi) {
  const int m = blockIdx.x, lane = threadIdx.x;
  if (m == 0 && lane == 0) *wcount = 0;
  float4 v = *reinterpret_cast<const float4*>(P + (size_t)m * 256 + lane * 4);
  float s = v.x * v.x + v.y * v.y + v.z * v.z + v.w * v.w;
  for (int off = 32; off > 0; off >>= 1) s += __shfl_xor(s, off, 64);
  const float qm = (counts[m] > 0) ? (1.0f / sqrtf(s)) : 0.0f;
  if (lane == 0) q[m] = qm;
  if (lane < 32) {
    const int kg = lane;  // 8 k-elements per lane
    const float* src = P + (size_t)m * 256 + kg * 8;
    float4 v0 = *reinterpret_cast<const float4*>(src);
    float4 v1 = *reinterpret_cast<const float4*>(src + 4);
    float pe[8] = {v0.x, v0.y, v0.z, v0.w, v1.x, v1.y, v1.z, v1.w};
    f16x8 hi;
#pragma unroll
    for (int t = 0; t < 8; ++t) hi[t] = (_Float16)(pe[t] * qm);
    const int dst = ((m >> 4) * 8 + (kg >> 2)) * 64 + (kg & 3) * 16 + (m & 15);
    bhi[dst] = hi;
  }
}

// ---------------- kernel 2: 1-term fp16 MFMA screen, barrier-free + explicit vmcnt fence ----
// 512 threads = 8 waves (2 rg x 4 cg). BM=128 rows; wave tile 64 rows x 64 protos per step.
// A: E hi fp16, K=256, 64KB LDS, XOR-swizzled (one stage barrier).
// B: WAVE-PRIVATE 2x4KB LDS double buffers via global_load_lds.
// r13 LESSON: global_load_lds writes LDS, not registers -- the compiler inserts NO waitcnt
// between the DMA and a later ds_read of that buffer. The per-step __syncthreads in r7/r12
// was the implicit fence. Barrier-free requires an EXPLICIT per-wave s_waitcnt vmcnt(0)
// before reading the buffer the previous step's DMA targeted (+ sched_barrier, rule #18).
// The fence waits only on this wave's own 4 DMAs, issued before the previous step's
// 16-MFMA cluster -> latency fully covered; no cross-wave lockstep.
__global__ __launch_bounds__(512) void screen_kernel(
    const float* __restrict__ E, const f16x8* __restrict__ bhi,
    int* __restrict__ out, int* __restrict__ wcount,
    int* __restrict__ wl, int wlcap) {
  __shared__ __align__(16) unsigned char ldsA[65536];  // 128 rows x 512B (hi fp16, K=256)
  __shared__ __align__(16) unsigned char ldsB[65536];  // 8 waves x 2 bufs x 4KB (wave-private)

  const int tid = threadIdx.x;
  const int wave = tid >> 6, lane = tid & 63;
  const int rg = wave >> 2, cg = wave & 3;
  const int g = lane >> 4, c = lane & 15;
  const int blockRow = blockIdx.x * 128;
  const char* bhiB = (const char*)bhi;
  char* ldsBw = (char*)ldsB + wave * 8192;  // this wave's private 2x4KB

  // ---- stage A once: E[blockRow..+128][0..256) f32 -> hi fp16, swizzled ----
  {
    const int row = tid >> 2, qq = tid & 3;  // 4 threads/row, 64 k each
    const float* src = E + (size_t)(blockRow + row) * 256 + qq * 64;
    const int rswz = (row & 7) << 4;
#pragma unroll
    for (int o = 0; o < 8; ++o) {
      float4 v0 = *reinterpret_cast<const float4*>(src + o * 8);
      float4 v1 = *reinterpret_cast<const float4*>(src + o * 8 + 4);
      float e[8] = {v0.x, v0.y, v0.z, v0.w, v1.x, v1.y, v1.z, v1.w};
      f16x8 hi;
#pragma unroll
      for (int t = 0; t < 8; ++t) hi[t] = (_Float16)e[t];
      const int byte = (row * 512 + (qq * 64 + o * 8) * 2) ^ rswz;
      *reinterpret_cast<f16x8*>(ldsA + byte) = hi;
    }
  }

  // ---- B stage: DMA step t=(pt,kc) into private buffer b (4 chunks = this wave's cg cols) ----
  auto stageB = [&](int b, int t) {
    const int ptn = t >> 3, kcn = t & 7;
    char* dstb = ldsBw + b * 4096;
#pragma unroll
    for (int fc = 0; fc < 4; ++fc) {
      const size_t src =
          (size_t)((((ptn * 16 + cg * 4 + fc) * 8 + kcn) << 10)) + (size_t)lane * 16;
      gload_lds16(bhiB + src, dstb + fc * 1024);
    }
  };

  stageB(0, 0);
  __syncthreads();  // A staged; barrier drains vmcnt -> buf0 valid

  // quantized top-2 per lane: 16 row-slots (row = rg*64 + (s>>2)*16 + g*4 + (s&3))
  unsigned t1[16], t2[16];
#pragma unroll
  for (int s = 0; s < 16; ++s) { t1[s] = 0u; t2[s] = 0u; }

#pragma unroll 1
  for (int pt = 0; pt < 4; ++pt) {
    f32x4 acc[4][4];
#pragma unroll
    for (int fr = 0; fr < 4; ++fr)
#pragma unroll
      for (int fc = 0; fc < 4; ++fc) acc[fr][fc] = (f32x4){0.f, 0.f, 0.f, 0.f};

#pragma unroll
    for (int kc = 0; kc < 8; ++kc) {
      const int t = pt * 8 + kc;
      const int buf = t & 1;  // compile-time within the unrolled kc loop

      // ---- fence: this wave's DMAs into `buf` (issued last step) must have landed ----
      if (t > 0) {
        asm volatile("s_waitcnt vmcnt(0)" ::: "memory");
        __builtin_amdgcn_sched_barrier(0);
      }
      // ---- phase 1: read fragments of buf (A from shared LDS, B from private LDS) ----
      f16x8 ah[4], bf[4];
#pragma unroll
      for (int fr = 0; fr < 4; ++fr) {
        const int rowA = rg * 64 + fr * 16 + c;
        const int ab = (rowA * 512 + kc * 64 + g * 16) ^ ((rowA & 7) << 4);
        ah[fr] = *reinterpret_cast<const f16x8*>(ldsA + ab);
      }
      {
        const char* bbase = ldsBw + buf * 4096 + (size_t)lane * 16;
#pragma unroll
        for (int fc = 0; fc < 4; ++fc)
          bf[fc] = *reinterpret_cast<const f16x8*>(bbase + fc * 1024);
      }
      // ---- phase 2: issue next step's DMA (hides under phase 3) ----
      if (t < 31) stageB(buf ^ 1, t + 1);
      // ---- phase 3: 16 MFMA ----
#pragma unroll
      for (int fr = 0; fr < 4; ++fr)
#pragma unroll
        for (int fc = 0; fc < 4; ++fc)
          acc[fr][fc] = __builtin_amdgcn_mfma_f32_16x16x32_f16(ah[fr], bf[fc], acc[fr][fc], 0, 0, 0);
    }

    // ---- fold this pt's 64 proto-columns (per cg) into quantized top-2 ----
#pragma unroll
    for (int fc = 0; fc < 4; ++fc) {
      const unsigned mp = (unsigned)(1023 - (pt * 256 + cg * 64 + fc * 16 + c));
#pragma unroll
      for (int fr = 0; fr < 4; ++fr)
#pragma unroll
        for (int reg = 0; reg < 4; ++reg) {
          const int s = fr * 4 + reg;
          const float v = acc[fr][fc][reg];
          const unsigned k = ((unsigned)fmaf(v, 32768.0f, 2097152.0f) << 10) | mp;
          const unsigned lo = (k < t1[s]) ? k : t1[s];
          t1[s] = (k > t1[s]) ? k : t1[s];
          t2[s] = (lo > t2[s]) ? lo : t2[s];
        }
    }
  }

  // ---- cross-lane top-2 merge over the 16 c-lanes sharing each row ----
#pragma unroll
  for (int s = 0; s < 16; ++s) {
#pragma unroll
    for (int off = 1; off <= 8; off <<= 1) {
      const unsigned o1 = (unsigned)__shfl_xor((int)t1[s], off);
      const unsigned o2 = (unsigned)__shfl_xor((int)t2[s], off);
      const unsigned lo = (o1 < t1[s]) ? o1 : t1[s];
      t1[s] = (o1 > t1[s]) ? o1 : t1[s];
      const unsigned hi2 = (o2 > t2[s]) ? o2 : t2[s];
      t2[s] = (lo > hi2) ? lo : hi2;
    }
  }

  __syncthreads();  // all LDS use done -> reuse ldsA for cross-cg merge
  unsigned* mg = reinterpret_cast<unsigned*>(ldsA);  // [128 rows][4 cg][2]
  if (c == 0) {
#pragma unroll
    for (int s = 0; s < 16; ++s) {
      const int row = rg * 64 + (s >> 2) * 16 + g * 4 + (s & 3);
      mg[(row * 4 + cg) * 2 + 0] = t1[s];
      mg[(row * 4 + cg) * 2 + 1] = t2[s];
    }
  }
  __syncthreads();
  if (tid < 128) {
    unsigned T1 = mg[(tid * 4 + 0) * 2 + 0], T2 = mg[(tid * 4 + 0) * 2 + 1];
#pragma unroll
    for (int w = 1; w < 4; ++w) {
      const unsigned o1 = mg[(tid * 4 + w) * 2 + 0], o2 = mg[(tid * 4 + w) * 2 + 1];
      const unsigned lo = (o1 < T1) ? o1 : T1;
      T1 = (o1 > T1) ? o1 : T1;
      const unsigned hi2 = (o2 > T2) ? o2 : T2;
      T2 = (lo > hi2) ? lo : hi2;
    }
    const int grow = blockRow + tid;
    out[grow] = 1023 - (int)(T1 & 1023u);
    const unsigned iq1 = T1 >> 10, iq2 = T2 >> 10;
    if ((int)(iq1 - iq2) < TAU_Q || iq1 < MASK_Q) {
      const int p = atomicAdd(wcount, 1);
      if (p < wlcap) wl[p] = grow;
    }
  }
}

// ---------------- kernel 3: exact f32 rescue over the worklist (16 rows/batch) ----------------
// Round-1-identical accumulation per (row, proto): ONE ascending-k fmaf chain over k=0..255
// (x,y,z,w within each float4), then v = acc*q, ties to the smaller proto index.
__global__ __launch_bounds__(256) void rescue_kernel(
    const float* __restrict__ E, const float* __restrict__ P,
    const float* __restrict__ q, int* __restrict__ out,
    const int* __restrict__ wcount, const int* __restrict__ wl, int wlcap) {
  __shared__ float Elds[16][260];
  __shared__ int rowsS[16];
  __shared__ float wv[16][4];
  __shared__ int wm[16][4];

  const int tid = threadIdx.x;
  const int wave = tid >> 6, lane = tid & 63;
  int total = *wcount;
  if (total > wlcap) total = wlcap;

  for (int b0 = blockIdx.x * 16; b0 < total; b0 += gridDim.x * 16) {
    const int nb = min(16, total - b0);
    __syncthreads();
    if (tid < 16) rowsS[tid] = wl[b0 + (tid < nb ? tid : 0)];
    __syncthreads();
#pragma unroll
    for (int u = 0; u < 4; ++u) {
      const int unit = u * 256 + tid, r = unit >> 6, k4 = unit & 63;
      *reinterpret_cast<float4*>(&Elds[r][k4 * 4]) =
          *reinterpret_cast<const float4*>(E + (size_t)rowsS[r] * 256 + k4 * 4);
    }
    __syncthreads();

    float acc[16][4];  // 16 rows x 4 protos (m = tid + 256*j)
#pragma unroll
    for (int r = 0; r < 16; ++r)
#pragma unroll
      for (int j = 0; j < 4; ++j) acc[r][j] = 0.f;

    for (int k16 = 0; k16 < 16; ++k16) {  // 16 consecutive k per step
#pragma unroll
      for (int jp = 0; jp < 2; ++jp) {    // protos in pairs (register budget)
        float4 pv[2][4];
#pragma unroll
        for (int jj = 0; jj < 2; ++jj) {
          const float* ps = P + (size_t)(tid + 256 * (jp * 2 + jj)) * 256 + k16 * 16;
#pragma unroll
          for (int u = 0; u < 4; ++u)
            pv[jj][u] = *reinterpret_cast<const float4*>(ps + u * 4);
        }
#pragma unroll
        for (int r = 0; r < 16; ++r) {
#pragma unroll
          for (int jj = 0; jj < 2; ++jj) {
            const int j = jp * 2 + jj;
            float a = acc[r][j];
#pragma unroll
            for (int u = 0; u < 4; ++u) {
              const float4 ev = *reinterpret_cast<const float4*>(&Elds[r][k16 * 16 + u * 4]);
              a = fmaf(pv[jj][u].x, ev.x, a);
              a = fmaf(pv[jj][u].y, ev.y, a);
              a = fmaf(pv[jj][u].z, ev.z, a);
              a = fmaf(pv[jj][u].w, ev.w, a);
            }
            acc[r][j] = a;
          }
        }
      }
    }

    float qv[4];
#pragma unroll
    for (int j = 0; j < 4; ++j) qv[j] = q[tid + 256 * j];

#pragma unroll
    for (int r = 0; r < 16; ++r) {
      float bv = -3.0e38f;
      int bm = 0;
#pragma unroll
      for (int j = 0; j < 4; ++j) {  // m ascending -> strict > keeps lowest m
        const float v = (qv[j] > 0.f) ? acc[r][j] * qv[j] : -1.0e30f;
        if (v > bv) { bv = v; bm = tid + 256 * j; }
      }
#pragma unroll
      for (int off = 1; off <= 32; off <<= 1) {
        const float ov = __shfl_xor(bv, off);
        const int om = __shfl_xor(bm, off);
        if (ov > bv || (ov == bv && om < bm)) { bv = ov; bm = om; }
      }
      if (lane == 0) { wv[r][wave] = bv; wm[r][wave] = bm; }
    }
    __syncthreads();
    if (tid < 16) {
      float bv = wv[tid][0];
      int bm = wm[tid][0];
#pragma unroll
      for (int w = 1; w < 4; ++w) {
        const float ov = wv[tid][w];
        const int om = wm[tid][w];
        if (ov > bv || (ov == bv && om < bm)) { bv = ov; bm = om; }
      }
      if (tid < nb) out[rowsS[tid]] = bm;
    }
    __syncthreads();
  }
}

extern "C" void kernel_launch(void* const* d_in, const int* in_sizes, int n_in,
                              void* d_out, int out_size, void* d_ws, size_t ws_size,
                              hipStream_t stream) {
  const float* E = (const float*)d_in[0];
  const float* P = (const float*)d_in[1];
  const int* counts = (const int*)d_in[2];
  const int M = in_sizes[2];            // 1024
  const int Dd = in_sizes[1] / M;       // 256
  const int N = in_sizes[0] / Dd;       // 65536
  int* out = (int*)d_out;

  // workspace: q (4KB) | wcount @4096 | bhi @8192 (512KB) | worklist @532480
  float* qv = (float*)d_ws;
  int* wcount = (int*)((char*)d_ws + 4096);
  f16x8* bhi = (f16x8*)((char*)d_ws + 8192);
  int* wl = (int*)((char*)d_ws + 8192 + 524288);
  long long cap = ((long long)ws_size - (8192 + 524288)) / 4;
  if (cap < 0) cap = 0;
  if (cap > N) cap = N;
  int wlcap = (int)cap;

  prep_kernel<<<M, 64, 0, stream>>>(P, counts, qv, wcount, bhi);
  screen_kernel<<<N / 128, 512, 0, stream>>>(E, bhi, out, wcount, wl, wlcap);
  rescue_kernel<<<256, 256, 0, stream>>>(E, P, qv, out, wcount, wl, wlcap);
}